// Round 7
// baseline (294.176 us; speedup 1.0000x reference)
//
#include <hip/hip_runtime.h>

#define NUM_USERS 50000
#define NUM_ITEMS 50000
#define N_NODES   100000
#define NNZ       3200000
#define EMB_DIM   64
#define N_LAYERS  3
#define BATCH     16384

#define NBUCK 512
#define ABITS 8                  // bucket = dst >> 8 (256 nodes/bucket, 391 used)
#define NODES_PER_BUCK 256
#define TILE_EDGES 8192
#define NBUCK_USED ((N_NODES + NODES_PER_BUCK - 1) / NODES_PER_BUCK)   // 391
#define CAP 9472                 // padded capacity (mean 8192 + node pads ~384 + >10 sigma slack)

typedef unsigned long long ull;
typedef float v2f __attribute__((ext_vector_type(2)));

// ---- bf16 helpers (RNE) ----
__device__ inline unsigned bf16pair(float a, float b) {
    unsigned ua = __float_as_uint(a), ub = __float_as_uint(b);
    unsigned r0 = (ua + 0x7fffu + ((ua >> 16) & 1u)) >> 16;
    unsigned r1 = (ub + 0x7fffu + ((ub >> 16) & 1u)) >> 16;
    return r0 | (r1 << 16);
}
__device__ inline float blo(unsigned u) { return __uint_as_float(u << 16); }
__device__ inline float bhi(unsigned u) { return __uint_as_float(u & 0xffff0000u); }

// packed 2xf32 ops (VOP3P; halves independent)
__device__ inline void pkfma(v2f& d, v2f a, v2f b) {
    asm("v_pk_fma_f32 %0, %1, %2, %0" : "+v"(d) : "v"(a), "v"(b));
}
__device__ inline void pkadd(v2f& d, v2f a) {
    asm("v_pk_add_f32 %0, %1, %0" : "+v"(d) : "v"(a));
}

// accumulate one edge's 8 bf16 dims (uint4) with UNscaled integer weight (r>>17).
// 2^-15 scale folded into epilogue (exact pow2 -> bit-identical). Zero rec -> w=0.
__device__ inline void accP(v2f& sA, v2f& sB, v2f& sC, v2f& sD, uint4 g, unsigned r) {
    float w = (float)(r >> 17);
    v2f w2 = {w, w};
    v2f e0 = {blo(g.x), bhi(g.x)};
    v2f e1 = {blo(g.y), bhi(g.y)};
    v2f e2 = {blo(g.z), bhi(g.z)};
    v2f e3 = {blo(g.w), bhi(g.w)};
    pkfma(sA, e0, w2);
    pkfma(sB, e1, w2);
    pkfma(sC, e2, w2);
    pkfma(sD, e3, w2);
}

// gather one uint4 (8 bf16 dims) of node src at dim-octet byte offset dOff.
__device__ inline uint4 gath(const unsigned char* __restrict__ base, unsigned r, unsigned dOff) {
    unsigned off = ((r & 0x1FFFFu) << 7) + dOff;
    return *(const uint4*)(base + off);
}

// butterfly reduce across eg (xor 8,16,32) on a packed pair
__device__ inline void wred(v2f& s) {
    v2f t;
    t.x = __shfl_xor(s.x, 8, 64);  t.y = __shfl_xor(s.y, 8, 64);  pkadd(s, t);
    t.x = __shfl_xor(s.x, 16, 64); t.y = __shfl_xor(s.y, 16, 64); pkadd(s, t);
    t.x = __shfl_xor(s.x, 32, 64); t.y = __shfl_xor(s.y, 32, 64); pkadd(s, t);
}

// ---- shared pull body (R1-proven, 50.6us @154MB): one WAVE per dst node.
// lane = (eg=lane>>3, d8=lane&7). dwordx4 record loads: lane owns 4 consecutive
// records of its eg's 4-record slot -> one VMEM per 32 records. cnt is the
// PADDED run length (mult of 4; pads are zero records -> w=0, row-0 gather).
__device__ inline void pull_node(const unsigned char* __restrict__ A16,
                                 unsigned* __restrict__ B16,
                                 const unsigned* __restrict__ sorted,
                                 int node, int start, int cnt, int lane) {
    int eg = lane >> 3;
    int d8 = lane & 7;
    unsigned dOff = (unsigned)d8 << 4;
    const unsigned* ep = sorted + start;     // 16B-aligned (partB pads)

    v2f sA = {0.f,0.f}, sB = {0.f,0.f}, sC = {0.f,0.f}, sD = {0.f,0.f};
    int j = 0;
    while (j + 32 <= cnt) {
        uint4 R = *(const uint4*)(ep + j + (eg << 2));   // records j+4eg..j+4eg+3
        uint4 g0 = gath(A16, R.x, dOff);
        uint4 g1 = gath(A16, R.y, dOff);
        uint4 g2 = gath(A16, R.z, dOff);
        uint4 g3 = gath(A16, R.w, dOff);
        accP(sA, sB, sC, sD, g0, R.x);
        accP(sA, sB, sC, sD, g1, R.y);
        accP(sA, sB, sC, sD, g2, R.z);
        accP(sA, sB, sC, sD, g3, R.w);
        j += 32;
    }
    int rem = cnt - j;                  // 0..28, mult of 4
    if (rem >= 16) {
        uint2 R = *(const uint2*)(ep + j + (eg << 1));   // records j+2eg, j+2eg+1
        uint4 g0 = gath(A16, R.x, dOff);
        uint4 g1 = gath(A16, R.y, dOff);
        accP(sA, sB, sC, sD, g0, R.x);
        accP(sA, sB, sC, sD, g1, R.y);
        j += 16; rem -= 16;
    }
    if (rem > 0) {                      // 4/8/12 records, one predicated round
        int i0 = j + eg, i1 = j + 8 + eg;
        unsigned r0 = (i0 < cnt) ? ep[i0] : 0u;   // r=0 -> w=0
        unsigned r1 = (i1 < cnt) ? ep[i1] : 0u;
        uint4 g0 = gath(A16, r0, dOff);
        uint4 g1 = gath(A16, r1, dOff);
        accP(sA, sB, sC, sD, g0, r0);
        accP(sA, sB, sC, sD, g1, r1);
    }

    wred(sA); wred(sB); wred(sC); wred(sD);

    if (eg == 0) {
        const float k15 = 1.f / 32768.f;   // fold fix15 weight scale (exact pow2)
        uint4 h;
        h.x = bf16pair(sA.x * k15, sA.y * k15);
        h.y = bf16pair(sB.x * k15, sB.y * k15);
        h.z = bf16pair(sC.x * k15, sC.y * k15);
        h.w = bf16pair(sD.x * k15, sD.y * k15);
        *(uint4*)(B16 + (((long long)node) << 5) + (d8 << 2)) = h;
    }
}

// init: E0(bf16) = concat(ue, ie). Block 0 inits bucket cursors.
__global__ void init_emb_kernel(const float* __restrict__ ue,
                                const float* __restrict__ ie,
                                unsigned* __restrict__ E0,
                                int* __restrict__ bucketCursor) {
    int idx = blockIdx.x * blockDim.x + threadIdx.x;   // per float4 (4 dims)
    if (blockIdx.x == 0 && threadIdx.x < 256) {
        bucketCursor[threadIdx.x]       = threadIdx.x * CAP;
        bucketCursor[threadIdx.x + 256] = (threadIdx.x + 256) * CAP;
    }
    const int total = N_NODES * (EMB_DIM / 4);
    if (idx >= total) return;
    const int uoff = NUM_USERS * (EMB_DIM / 4);
    float4 v;
    if (idx < uoff) v = ((const float4*)ue)[idx];
    else            v = ((const float4*)ie)[idx - uoff];
    uint2 h;
    h.x = bf16pair(v.x, v.y);
    h.y = bf16pair(v.z, v.w);
    ((uint2*)E0)[idx] = h;
}

// partA: partition edges into padded dst-bucket regions. 1024 threads, 8/thread.
// Writes FINAL record format rec32 = src(17) | fix15(val)<<17 (4B) plus a
// separate dstLocal byte (1B) -> 5 B/edge tmp traffic instead of 8.
__global__ void partA_kernel(const float* __restrict__ ev,
                             const int*  __restrict__ es,
                             const int*  __restrict__ ed,
                             int* __restrict__ bucketCursor,
                             unsigned* __restrict__ tmpR,
                             unsigned char* __restrict__ tmpD) {
    __shared__ int hist[NBUCK];
    __shared__ int base[NBUCK];
    __shared__ int cnt2[NBUCK];
    int tid = threadIdx.x;            // 1024
    int e0 = blockIdx.x * TILE_EDGES;

    int      myDst[8];
    unsigned myR[8];

    for (int i = tid; i < NBUCK; i += 1024) hist[i] = 0;
    __syncthreads();

    #pragma unroll
    for (int k = 0; k < 8; ++k) {
        int e = e0 + k * 1024 + tid;
        if (e < NNZ) {
            myDst[k] = ed[e];
            unsigned q = (unsigned)fminf(ev[e] * 32768.f + 0.5f, 32767.f);
            myR[k] = (unsigned)es[e] | (q << 17);
            atomicAdd(&hist[((unsigned)myDst[k]) >> ABITS], 1);
        } else {
            myDst[k] = -1;
        }
    }
    __syncthreads();

    for (int i = tid; i < NBUCK; i += 1024) {
        int c = hist[i];
        base[i] = c ? atomicAdd(&bucketCursor[i], c) : 0;
        cnt2[i] = 0;
    }
    __syncthreads();

    #pragma unroll
    for (int k = 0; k < 8; ++k) {
        int dst = myDst[k];
        if (dst < 0) continue;
        int b = ((unsigned)dst) >> ABITS;
        int pos = base[b] + atomicAdd(&cnt2[b], 1);
        if (pos < (b + 1) * CAP) {   // statistically unreachable overflow guard
            tmpR[pos] = myR[k];
            tmpD[pos] = (unsigned char)(dst & (NODES_PER_BUCK - 1));
        }
    }
}

// partB: per bucket — 256-node histogram, node-level scan of pad4(count), scatter
// records (already final format) to padded positions; pads zeroed.
// deg[node] = PADDED run length (mult of 4). rowStart 16B-aligned.
__global__ void partB_kernel(const unsigned* __restrict__ tmpR,
                             const unsigned char* __restrict__ tmpD,
                             const int* __restrict__ bucketCursor,
                             int* __restrict__ rowStart,
                             int* __restrict__ deg,
                             unsigned* __restrict__ sorted) {
    __shared__ int cnt[NODES_PER_BUCK];
    __shared__ int nsc[NODES_PER_BUCK];     // scan of pad4(count)
    __shared__ int nstart[NODES_PER_BUCK];
    __shared__ int cur[NODES_PER_BUCK];
    int b = blockIdx.x;
    int tid = threadIdx.x;           // 1024
    int nodeLo = b << ABITS;
    int startE = b * CAP;
    int endE   = bucketCursor[b];    // base + records in bucket

    if (tid < NODES_PER_BUCK) cnt[tid] = 0;
    __syncthreads();

    unsigned myRec[9];
    int myDl[9];
    int nRec = 0;
    #pragma unroll
    for (int k = 0; k < 9; ++k) {
        int i = startE + k * 1024 + tid;
        if (i < endE) {
            myRec[k] = tmpR[i];
            myDl[k]  = (int)tmpD[i];
            nRec = k + 1;
            atomicAdd(&cnt[myDl[k]], 1);
        }
    }
    __syncthreads();

    int p4 = 0;
    if (tid < NODES_PER_BUCK) {
        p4 = (cnt[tid] + 3) & ~3;
        nsc[tid] = p4;
    }
    __syncthreads();
    for (int o = 1; o < NODES_PER_BUCK; o <<= 1) {
        int add = 0;
        if (tid < NODES_PER_BUCK && tid >= o) add = nsc[tid - o];
        __syncthreads();
        if (tid < NODES_PER_BUCK) nsc[tid] += add;
        __syncthreads();
    }
    if (tid < NODES_PER_BUCK) {
        int ns = startE + nsc[tid] - p4;   // 16B-aligned (startE%4==0, scan of x4)
        nstart[tid] = ns;
        cur[tid] = ns;
        int node = nodeLo + tid;
        if (node < N_NODES) {
            rowStart[node] = ns;
            deg[node] = p4;                // PADDED length; pads zeroed below
        }
    }
    __syncthreads();

    for (int k = 0; k < nRec; ++k) {
        int pos = atomicAdd(&cur[myDl[k]], 1);
        if (pos < startE + CAP) sorted[pos] = myRec[k];  // overflow guard
    }
    __syncthreads();

    if (tid < NODES_PER_BUCK) {        // zero the <=3 pad slots at each node tail
        int end = nstart[tid] + ((cnt[tid] + 3) & ~3);
        for (int p = cur[tid]; p < end; ++p)
            if (p < startE + CAP) sorted[p] = 0;
    }
}

// ---- pull_sync (ungated layers): one wave per node.
__global__ void pull_sync_kernel(const unsigned char* __restrict__ A16,
                                 unsigned* __restrict__ B16,
                                 const unsigned* __restrict__ sorted,
                                 const int* __restrict__ rowStart,
                                 const int* __restrict__ deg) {
    int t = blockIdx.x * blockDim.x + threadIdx.x;
    int node = __builtin_amdgcn_readfirstlane(t >> 6);
    if (node >= N_NODES) return;
    int start = rowStart[node];        // scalar (node in SGPR)
    int cnt   = deg[node];
    pull_node(A16, B16, sorted, node, start, cnt, t & 63);
}

// ---- pull_gated (layer 3): one wave per batch ENTRY (dense sweep of the 32768
// user/item indices — no flags, no dead waves). Duplicate entries store
// byte-identical rows (benign race).
__global__ void pull_gated_kernel(const unsigned char* __restrict__ A16,
                                  unsigned* __restrict__ B16,
                                  const unsigned* __restrict__ sorted,
                                  const int* __restrict__ rowStart,
                                  const int* __restrict__ deg,
                                  const int* __restrict__ users,
                                  const int* __restrict__ items) {
    int t = blockIdx.x * blockDim.x + threadIdx.x;
    int e = __builtin_amdgcn_readfirstlane(t >> 6);
    if (e >= 2 * BATCH) return;
    int node = (e < BATCH) ? users[e] : (NUM_USERS + items[e - BATCH]);
    node = __builtin_amdgcn_readfirstlane(node);
    int start = rowStart[node];
    int cnt   = deg[node];
    pull_node(A16, B16, sorted, node, start, cnt, t & 63);
}

// dot: half-wave (32 lanes) per batch element; lane covers 2 dims (one uint).
// gamma = dot( sum_l U_l , sum_l I_l ) / 16, layers read from E0,B1,B2,B3.
__global__ void dot_kernel(const unsigned* __restrict__ E0,
                           const unsigned* __restrict__ B1,
                           const unsigned* __restrict__ B2,
                           const unsigned* __restrict__ B3,
                           const int* __restrict__ users,
                           const int* __restrict__ items,
                           float* __restrict__ out) {
    int t = blockIdx.x * blockDim.x + threadIdx.x;
    int b = t >> 5;
    int lane = t & 31;
    if (b >= BATCH) return;
    long long uo = ((long long)users[b] << 5) + lane;
    long long io = ((long long)(items[b] + NUM_USERS) << 5) + lane;
    unsigned a0 = E0[uo], a1 = B1[uo], a2 = B2[uo], a3 = B3[uo];
    unsigned c0 = E0[io], c1 = B1[io], c2 = B2[io], c3 = B3[io];
    float ux = (blo(a0) + blo(a1)) + (blo(a2) + blo(a3));
    float uy = (bhi(a0) + bhi(a1)) + (bhi(a2) + bhi(a3));
    float ix = (blo(c0) + blo(c1)) + (blo(c2) + blo(c3));
    float iy = (bhi(c0) + bhi(c1)) + (bhi(c2) + bhi(c3));
    float p = ux * ix + uy * iy;
    #pragma unroll
    for (int off = 16; off >= 1; off >>= 1)
        p += __shfl_xor(p, off, 64);   // stays within the aligned 32-group
    if (lane == 0) out[b] = p * 0.0625f;
}

extern "C" void kernel_launch(void* const* d_in, const int* in_sizes, int n_in,
                              void* d_out, int out_size, void* d_ws, size_t ws_size,
                              hipStream_t stream) {
    const float* user_emb = (const float*)d_in[0];
    const float* item_emb = (const float*)d_in[1];
    const float* edge_val = (const float*)d_in[2];
    const int*   edge_src = (const int*)d_in[3];
    const int*   edge_dst = (const int*)d_in[4];
    const int*   users    = (const int*)d_in[5];
    const int*   items    = (const int*)d_in[6];
    float* out = (float*)d_out;

    const size_t emb16Bytes = (size_t)N_NODES * EMB_DIM * 2;               // 12.8 MB
    const size_t sortBytes  = (size_t)NBUCK_USED * CAP * sizeof(unsigned); // 14.8 MB
    const size_t tmpRBytes  = (size_t)NBUCK_USED * CAP * sizeof(unsigned); // 14.8 MB
    const size_t tmpDBytes  = (size_t)NBUCK_USED * CAP;                    //  3.7 MB
    const size_t nodeBytes  = (size_t)N_NODES * sizeof(int);               // 400 KB

    char* w = (char*)d_ws;
    unsigned* E0           = (unsigned*)(w); w += emb16Bytes;
    unsigned* B1           = (unsigned*)(w); w += emb16Bytes;
    unsigned* B2           = (unsigned*)(w); w += emb16Bytes;
    unsigned* B3           = (unsigned*)(w); w += emb16Bytes;
    unsigned* sorted       = (unsigned*)(w); w += sortBytes;
    unsigned* tmpR         = (unsigned*)(w); w += tmpRBytes;
    unsigned char* tmpD    = (unsigned char*)(w); w += (tmpDBytes + 15) & ~15ull;
    int*      deg          = (int*)(w);      w += nodeBytes;
    int*      rowStart     = (int*)(w);      w += nodeBytes;
    int*      bucketCursor = (int*)(w);      w += NBUCK * sizeof(int);

    const int vecTotal   = N_NODES * (EMB_DIM / 4);
    const int initBlocks = (vecTotal + 255) / 256;
    const int tileBlocks = (NNZ + TILE_EDGES - 1) / TILE_EDGES;   // 391

    init_emb_kernel<<<initBlocks, 256, 0, stream>>>(user_emb, item_emb, E0, bucketCursor);

    partA_kernel<<<tileBlocks, 1024, 0, stream>>>(edge_val, edge_src, edge_dst,
                                                  bucketCursor, tmpR, tmpD);
    partB_kernel<<<NBUCK_USED, 1024, 0, stream>>>(tmpR, tmpD, bucketCursor,
                                                  rowStart, deg, sorted);

    const int pullBlocks = (N_NODES * 64 + 255) / 256;            // 1 node/wave
    pull_sync_kernel<<<pullBlocks, 256, 0, stream>>>((const unsigned char*)E0, B1,
                                                     sorted, rowStart, deg);
    pull_sync_kernel<<<pullBlocks, 256, 0, stream>>>((const unsigned char*)B1, B2,
                                                     sorted, rowStart, deg);

    const int gatedBlocks = (2 * BATCH * 64 + 255) / 256;         // 1 entry/wave
    pull_gated_kernel<<<gatedBlocks, 256, 0, stream>>>((const unsigned char*)B2, B3,
                                                       sorted, rowStart, deg, users, items);

    const int dotBlocks = (BATCH * 32 + 255) / 256;
    dot_kernel<<<dotBlocks, 256, 0, stream>>>(E0, B1, B2, B3, users, items, out);
}

// Round 8
// 278.453 us; speedup vs baseline: 1.0565x; 1.0565x over previous
//
#include <hip/hip_runtime.h>

#define NUM_USERS 50000
#define NUM_ITEMS 50000
#define N_NODES   100000
#define NNZ       3200000
#define EMB_DIM   64
#define N_LAYERS  3
#define BATCH     16384

#define NBUCK 512
#define ABITS 8                  // bucket = dst >> 8 (256 nodes/bucket, 391 used)
#define NODES_PER_BUCK 256
#define TILE_EDGES 4096          // counting-sort tile (32KB LDS records)
#define NBUCK_USED ((N_NODES + NODES_PER_BUCK - 1) / NODES_PER_BUCK)   // 391
#define CAP 9472                 // padded capacity (mean 8192 + node pads ~384 + >10 sigma slack)

typedef unsigned long long ull;
typedef float v2f __attribute__((ext_vector_type(2)));

// ---- bf16 helpers (RNE) ----
__device__ inline unsigned bf16pair(float a, float b) {
    unsigned ua = __float_as_uint(a), ub = __float_as_uint(b);
    unsigned r0 = (ua + 0x7fffu + ((ua >> 16) & 1u)) >> 16;
    unsigned r1 = (ub + 0x7fffu + ((ub >> 16) & 1u)) >> 16;
    return r0 | (r1 << 16);
}
__device__ inline float blo(unsigned u) { return __uint_as_float(u << 16); }
__device__ inline float bhi(unsigned u) { return __uint_as_float(u & 0xffff0000u); }

// packed 2xf32 ops (VOP3P; halves independent)
__device__ inline void pkfma(v2f& d, v2f a, v2f b) {
    asm("v_pk_fma_f32 %0, %1, %2, %0" : "+v"(d) : "v"(a), "v"(b));
}
__device__ inline void pkadd(v2f& d, v2f a) {
    asm("v_pk_add_f32 %0, %1, %0" : "+v"(d) : "v"(a));
}

// accumulate one edge's 8 bf16 dims (uint4) with UNscaled integer weight (r>>17).
// 2^-15 scale folded into epilogue (exact pow2 -> bit-identical). Zero rec -> w=0.
__device__ inline void accP(v2f& sA, v2f& sB, v2f& sC, v2f& sD, uint4 g, unsigned r) {
    float w = (float)(r >> 17);
    v2f w2 = {w, w};
    v2f e0 = {blo(g.x), bhi(g.x)};
    v2f e1 = {blo(g.y), bhi(g.y)};
    v2f e2 = {blo(g.z), bhi(g.z)};
    v2f e3 = {blo(g.w), bhi(g.w)};
    pkfma(sA, e0, w2);
    pkfma(sB, e1, w2);
    pkfma(sC, e2, w2);
    pkfma(sD, e3, w2);
}

// gather one uint4 (8 bf16 dims) of node src at dim-octet byte offset dOff.
__device__ inline uint4 gath(const unsigned char* __restrict__ base, unsigned r, unsigned dOff) {
    unsigned off = ((r & 0x1FFFFu) << 7) + dOff;
    return *(const uint4*)(base + off);
}

// butterfly reduce across eg (xor 8,16,32) on a packed pair
__device__ inline void wred(v2f& s) {
    v2f t;
    t.x = __shfl_xor(s.x, 8, 64);  t.y = __shfl_xor(s.y, 8, 64);  pkadd(s, t);
    t.x = __shfl_xor(s.x, 16, 64); t.y = __shfl_xor(s.y, 16, 64); pkadd(s, t);
    t.x = __shfl_xor(s.x, 32, 64); t.y = __shfl_xor(s.y, 32, 64); pkadd(s, t);
}

// ---- shared pull body (R1/R7-proven, 51.2us @154MB): one WAVE per dst node.
// lane = (eg=lane>>3, d8=lane&7). dwordx4 record loads: lane owns 4 consecutive
// records of its eg's slot -> one VMEM per 32 records. cnt is the PADDED run
// length (mult of 4; pads are zero records -> w=0, row-0 gather).
__device__ inline void pull_node(const unsigned char* __restrict__ A16,
                                 unsigned* __restrict__ B16,
                                 const unsigned* __restrict__ sorted,
                                 int node, int start, int cnt, int lane) {
    int eg = lane >> 3;
    int d8 = lane & 7;
    unsigned dOff = (unsigned)d8 << 4;
    const unsigned* ep = sorted + start;     // 16B-aligned (partB pads)

    v2f sA = {0.f,0.f}, sB = {0.f,0.f}, sC = {0.f,0.f}, sD = {0.f,0.f};
    int j = 0;
    while (j + 32 <= cnt) {
        uint4 R = *(const uint4*)(ep + j + (eg << 2));   // records j+4eg..j+4eg+3
        uint4 g0 = gath(A16, R.x, dOff);
        uint4 g1 = gath(A16, R.y, dOff);
        uint4 g2 = gath(A16, R.z, dOff);
        uint4 g3 = gath(A16, R.w, dOff);
        accP(sA, sB, sC, sD, g0, R.x);
        accP(sA, sB, sC, sD, g1, R.y);
        accP(sA, sB, sC, sD, g2, R.z);
        accP(sA, sB, sC, sD, g3, R.w);
        j += 32;
    }
    int rem = cnt - j;                  // 0..28, mult of 4
    if (rem >= 16) {
        uint2 R = *(const uint2*)(ep + j + (eg << 1));   // records j+2eg, j+2eg+1
        uint4 g0 = gath(A16, R.x, dOff);
        uint4 g1 = gath(A16, R.y, dOff);
        accP(sA, sB, sC, sD, g0, R.x);
        accP(sA, sB, sC, sD, g1, R.y);
        j += 16; rem -= 16;
    }
    if (rem > 0) {                      // 4/8/12 records, one predicated round
        int i0 = j + eg, i1 = j + 8 + eg;
        unsigned r0 = (i0 < cnt) ? ep[i0] : 0u;   // r=0 -> w=0
        unsigned r1 = (i1 < cnt) ? ep[i1] : 0u;
        uint4 g0 = gath(A16, r0, dOff);
        uint4 g1 = gath(A16, r1, dOff);
        accP(sA, sB, sC, sD, g0, r0);
        accP(sA, sB, sC, sD, g1, r1);
    }

    wred(sA); wred(sB); wred(sC); wred(sD);

    if (eg == 0) {
        const float k15 = 1.f / 32768.f;   // fold fix15 weight scale (exact pow2)
        uint4 h;
        h.x = bf16pair(sA.x * k15, sA.y * k15);
        h.y = bf16pair(sB.x * k15, sB.y * k15);
        h.z = bf16pair(sC.x * k15, sC.y * k15);
        h.w = bf16pair(sD.x * k15, sD.y * k15);
        *(uint4*)(B16 + (((long long)node) << 5) + (d8 << 2)) = h;
    }
}

// init: E0(bf16) = concat(ue, ie). Block 0 inits bucket cursors.
__global__ void init_emb_kernel(const float* __restrict__ ue,
                                const float* __restrict__ ie,
                                unsigned* __restrict__ E0,
                                int* __restrict__ bucketCursor) {
    int idx = blockIdx.x * blockDim.x + threadIdx.x;   // per float4 (4 dims)
    if (blockIdx.x == 0 && threadIdx.x < 256) {
        bucketCursor[threadIdx.x]       = threadIdx.x * CAP;
        bucketCursor[threadIdx.x + 256] = (threadIdx.x + 256) * CAP;
    }
    const int total = N_NODES * (EMB_DIM / 4);
    if (idx >= total) return;
    const int uoff = NUM_USERS * (EMB_DIM / 4);
    float4 v;
    if (idx < uoff) v = ((const float4*)ue)[idx];
    else            v = ((const float4*)ie)[idx - uoff];
    uint2 h;
    h.x = bf16pair(v.x, v.y);
    h.y = bf16pair(v.z, v.w);
    ((uint2*)E0)[idx] = h;
}

// partA: counting-sort each 4096-edge tile by bucket ENTIRELY IN LDS, then write
// contiguous per-bucket segments (coalesced) at positions from ONE global
// atomicAdd per (bucket, tile). This removes the scattered global write whose
// cross-XCD line thrash (~128B/edge hidden traffic) dominated partA.
// LDS rec: rec32(src|q15<<17) | dl8<<32 | bucket9<<40. 40KB static LDS.
__global__ void partA_kernel(const float* __restrict__ ev,
                             const int*  __restrict__ es,
                             const int*  __restrict__ ed,
                             int* __restrict__ bucketCursor,
                             ull* __restrict__ tmp) {
    __shared__ ull  recs[TILE_EDGES];      // 32KB
    __shared__ int  hist[NBUCK];
    __shared__ int  incl[NBUCK];           // inclusive scan of hist
    __shared__ int  gbase[NBUCK];
    __shared__ int  cur[NBUCK];
    int tid = threadIdx.x;                 // 1024
    int e0 = blockIdx.x * TILE_EDGES;
    int nEdge = NNZ - e0; if (nEdge > TILE_EDGES) nEdge = TILE_EDGES;

    if (tid < NBUCK) hist[tid] = 0;
    __syncthreads();

    ull myRec[4]; int myB[4]; int nMy = 0;
    #pragma unroll
    for (int k = 0; k < 4; ++k) {
        int e = e0 + k * 1024 + tid;
        if (e < NNZ) {
            int dst = ed[e];
            unsigned q = (unsigned)fminf(ev[e] * 32768.f + 0.5f, 32767.f);
            unsigned rec = (unsigned)es[e] | (q << 17);
            int b = ((unsigned)dst) >> ABITS;
            myRec[k] = (ull)rec | ((ull)(unsigned)(dst & (NODES_PER_BUCK - 1)) << 32)
                     | ((ull)(unsigned)b << 40);
            myB[k] = b;
            nMy = k + 1;                   // e grows with k -> contiguous prefix
            atomicAdd(&hist[b], 1);
        }
    }
    __syncthreads();

    if (tid < NBUCK) incl[tid] = hist[tid];
    __syncthreads();
    for (int o = 1; o < NBUCK; o <<= 1) {
        int v = 0;
        if (tid < NBUCK && tid >= o) v = incl[tid - o];
        __syncthreads();
        if (tid < NBUCK) incl[tid] += v;
        __syncthreads();
    }
    if (tid < NBUCK) {
        int c = hist[tid];
        cur[tid] = incl[tid] - c;          // local segment start (exclusive scan)
        gbase[tid] = c ? atomicAdd(&bucketCursor[tid], c) : 0;
    }
    __syncthreads();

    for (int k = 0; k < nMy; ++k) {        // LDS scatter (cheap, on-chip)
        int p = atomicAdd(&cur[myB[k]], 1);
        recs[p] = myRec[k];
    }
    __syncthreads();

    for (int p = tid; p < nEdge; p += 1024) {   // coalesced segment copy-out
        ull r = recs[p];
        int b = (int)((r >> 40) & 511u);
        int local = p - (incl[b] - hist[b]);
        int gpos = gbase[b] + local;
        if (gpos < (b + 1) * CAP) tmp[gpos] = r;   // overflow guard (stat. unreachable)
    }
}

// partB: per bucket — 256-node histogram, node-level scan of pad4(count), scatter
// records (already final format in lo32; dl in bits[39:32]) to padded positions;
// pads zeroed. deg[node] = PADDED run length (mult of 4). rowStart 16B-aligned.
__global__ void partB_kernel(const ull* __restrict__ tmp,
                             const int* __restrict__ bucketCursor,
                             int* __restrict__ rowStart,
                             int* __restrict__ deg,
                             unsigned* __restrict__ sorted) {
    __shared__ int cnt[NODES_PER_BUCK];
    __shared__ int nsc[NODES_PER_BUCK];     // scan of pad4(count)
    __shared__ int nstart[NODES_PER_BUCK];
    __shared__ int cur[NODES_PER_BUCK];
    int b = blockIdx.x;
    int tid = threadIdx.x;           // 1024
    int nodeLo = b << ABITS;
    int startE = b * CAP;
    int endE   = bucketCursor[b];    // base + records in bucket

    if (tid < NODES_PER_BUCK) cnt[tid] = 0;
    __syncthreads();

    unsigned myRec[9];
    int myDl[9];
    int nRec = 0;
    #pragma unroll
    for (int k = 0; k < 9; ++k) {
        int i = startE + k * 1024 + tid;
        if (i < endE) {
            ull r = tmp[i];
            myRec[k] = (unsigned)r;
            myDl[k]  = (int)((r >> 32) & 255u);
            nRec = k + 1;
            atomicAdd(&cnt[myDl[k]], 1);
        }
    }
    __syncthreads();

    int p4 = 0;
    if (tid < NODES_PER_BUCK) {
        p4 = (cnt[tid] + 3) & ~3;
        nsc[tid] = p4;
    }
    __syncthreads();
    for (int o = 1; o < NODES_PER_BUCK; o <<= 1) {
        int add = 0;
        if (tid < NODES_PER_BUCK && tid >= o) add = nsc[tid - o];
        __syncthreads();
        if (tid < NODES_PER_BUCK) nsc[tid] += add;
        __syncthreads();
    }
    if (tid < NODES_PER_BUCK) {
        int ns = startE + nsc[tid] - p4;   // 16B-aligned (startE%4==0, scan of x4)
        nstart[tid] = ns;
        cur[tid] = ns;
        int node = nodeLo + tid;
        if (node < N_NODES) {
            rowStart[node] = ns;
            deg[node] = p4;                // PADDED length; pads zeroed below
        }
    }
    __syncthreads();

    for (int k = 0; k < nRec; ++k) {
        int pos = atomicAdd(&cur[myDl[k]], 1);
        if (pos < startE + CAP) sorted[pos] = myRec[k];  // overflow guard
    }
    __syncthreads();

    if (tid < NODES_PER_BUCK) {        // zero the <=3 pad slots at each node tail
        int end = nstart[tid] + ((cnt[tid] + 3) & ~3);
        for (int p = cur[tid]; p < end; ++p)
            if (p < startE + CAP) sorted[p] = 0;
    }
}

// ---- pull_sync (ungated layers): one wave per node.
__global__ void pull_sync_kernel(const unsigned char* __restrict__ A16,
                                 unsigned* __restrict__ B16,
                                 const unsigned* __restrict__ sorted,
                                 const int* __restrict__ rowStart,
                                 const int* __restrict__ deg) {
    int t = blockIdx.x * blockDim.x + threadIdx.x;
    int node = __builtin_amdgcn_readfirstlane(t >> 6);
    if (node >= N_NODES) return;
    int start = rowStart[node];        // scalar (node in SGPR)
    int cnt   = deg[node];
    pull_node(A16, B16, sorted, node, start, cnt, t & 63);
}

// ---- pull_gated (layer 3): one wave per batch ENTRY (dense sweep of the 32768
// user/item indices — no flags, no dead waves). Duplicate entries store
// byte-identical rows (benign race).
__global__ void pull_gated_kernel(const unsigned char* __restrict__ A16,
                                  unsigned* __restrict__ B16,
                                  const unsigned* __restrict__ sorted,
                                  const int* __restrict__ rowStart,
                                  const int* __restrict__ deg,
                                  const int* __restrict__ users,
                                  const int* __restrict__ items) {
    int t = blockIdx.x * blockDim.x + threadIdx.x;
    int e = __builtin_amdgcn_readfirstlane(t >> 6);
    if (e >= 2 * BATCH) return;
    int node = (e < BATCH) ? users[e] : (NUM_USERS + items[e - BATCH]);
    node = __builtin_amdgcn_readfirstlane(node);
    int start = rowStart[node];
    int cnt   = deg[node];
    pull_node(A16, B16, sorted, node, start, cnt, t & 63);
}

// dot: half-wave (32 lanes) per batch element; lane covers 2 dims (one uint).
// gamma = dot( sum_l U_l , sum_l I_l ) / 16, layers read from E0,B1,B2,B3.
__global__ void dot_kernel(const unsigned* __restrict__ E0,
                           const unsigned* __restrict__ B1,
                           const unsigned* __restrict__ B2,
                           const unsigned* __restrict__ B3,
                           const int* __restrict__ users,
                           const int* __restrict__ items,
                           float* __restrict__ out) {
    int t = blockIdx.x * blockDim.x + threadIdx.x;
    int b = t >> 5;
    int lane = t & 31;
    if (b >= BATCH) return;
    long long uo = ((long long)users[b] << 5) + lane;
    long long io = ((long long)(items[b] + NUM_USERS) << 5) + lane;
    unsigned a0 = E0[uo], a1 = B1[uo], a2 = B2[uo], a3 = B3[uo];
    unsigned c0 = E0[io], c1 = B1[io], c2 = B2[io], c3 = B3[io];
    float ux = (blo(a0) + blo(a1)) + (blo(a2) + blo(a3));
    float uy = (bhi(a0) + bhi(a1)) + (bhi(a2) + bhi(a3));
    float ix = (blo(c0) + blo(c1)) + (blo(c2) + blo(c3));
    float iy = (bhi(c0) + bhi(c1)) + (bhi(c2) + bhi(c3));
    float p = ux * ix + uy * iy;
    #pragma unroll
    for (int off = 16; off >= 1; off >>= 1)
        p += __shfl_xor(p, off, 64);   // stays within the aligned 32-group
    if (lane == 0) out[b] = p * 0.0625f;
}

extern "C" void kernel_launch(void* const* d_in, const int* in_sizes, int n_in,
                              void* d_out, int out_size, void* d_ws, size_t ws_size,
                              hipStream_t stream) {
    const float* user_emb = (const float*)d_in[0];
    const float* item_emb = (const float*)d_in[1];
    const float* edge_val = (const float*)d_in[2];
    const int*   edge_src = (const int*)d_in[3];
    const int*   edge_dst = (const int*)d_in[4];
    const int*   users    = (const int*)d_in[5];
    const int*   items    = (const int*)d_in[6];
    float* out = (float*)d_out;

    const size_t emb16Bytes = (size_t)N_NODES * EMB_DIM * 2;               // 12.8 MB
    const size_t sortBytes  = (size_t)NBUCK_USED * CAP * sizeof(unsigned); // 14.8 MB
    const size_t tmpBytes   = (size_t)NBUCK_USED * CAP * sizeof(ull);      // 29.6 MB
    const size_t nodeBytes  = (size_t)N_NODES * sizeof(int);               // 400 KB

    char* w = (char*)d_ws;
    unsigned* E0           = (unsigned*)(w); w += emb16Bytes;
    unsigned* B1           = (unsigned*)(w); w += emb16Bytes;
    unsigned* B2           = (unsigned*)(w); w += emb16Bytes;
    unsigned* B3           = (unsigned*)(w); w += emb16Bytes;
    unsigned* sorted       = (unsigned*)(w); w += sortBytes;
    ull*      tmp          = (ull*)(w);      w += tmpBytes;
    int*      deg          = (int*)(w);      w += nodeBytes;
    int*      rowStart     = (int*)(w);      w += nodeBytes;
    int*      bucketCursor = (int*)(w);      w += NBUCK * sizeof(int);

    const int vecTotal   = N_NODES * (EMB_DIM / 4);
    const int initBlocks = (vecTotal + 255) / 256;
    const int tileBlocks = (NNZ + TILE_EDGES - 1) / TILE_EDGES;   // 782

    init_emb_kernel<<<initBlocks, 256, 0, stream>>>(user_emb, item_emb, E0, bucketCursor);

    partA_kernel<<<tileBlocks, 1024, 0, stream>>>(edge_val, edge_src, edge_dst,
                                                  bucketCursor, tmp);
    partB_kernel<<<NBUCK_USED, 1024, 0, stream>>>(tmp, bucketCursor,
                                                  rowStart, deg, sorted);

    const int pullBlocks = (N_NODES * 64 + 255) / 256;            // 1 node/wave
    pull_sync_kernel<<<pullBlocks, 256, 0, stream>>>((const unsigned char*)E0, B1,
                                                     sorted, rowStart, deg);
    pull_sync_kernel<<<pullBlocks, 256, 0, stream>>>((const unsigned char*)B1, B2,
                                                     sorted, rowStart, deg);

    const int gatedBlocks = (2 * BATCH * 64 + 255) / 256;         // 1 entry/wave
    pull_gated_kernel<<<gatedBlocks, 256, 0, stream>>>((const unsigned char*)B2, B3,
                                                       sorted, rowStart, deg, users, items);

    const int dotBlocks = (BATCH * 32 + 255) / 256;
    dot_kernel<<<dotBlocks, 256, 0, stream>>>(E0, B1, B2, B3, users, items, out);
}

// Round 10
// 277.958 us; speedup vs baseline: 1.0583x; 1.0018x over previous
//
#include <hip/hip_runtime.h>

#define NUM_USERS 50000
#define NUM_ITEMS 50000
#define N_NODES   100000
#define NNZ       3200000
#define EMB_DIM   64
#define N_LAYERS  3
#define BATCH     16384

#define NBUCK 512
#define ABITS 8                  // bucket = dst >> 8 (256 nodes/bucket, 391 used)
#define NODES_PER_BUCK 256
#define TILE_EDGES 4096          // counting-sort tile (32KB LDS records)
#define NBUCK_USED ((N_NODES + NODES_PER_BUCK - 1) / NODES_PER_BUCK)   // 391
#define CAP 9472                 // padded capacity (mean 8192 + node pads ~384 + >10 sigma slack)

typedef unsigned long long ull;
typedef float v2f __attribute__((ext_vector_type(2)));

// ---- bf16 helpers (RNE) ----
__device__ inline unsigned bf16pair(float a, float b) {
    unsigned ua = __float_as_uint(a), ub = __float_as_uint(b);
    unsigned r0 = (ua + 0x7fffu + ((ua >> 16) & 1u)) >> 16;
    unsigned r1 = (ub + 0x7fffu + ((ub >> 16) & 1u)) >> 16;
    return r0 | (r1 << 16);
}
__device__ inline float blo(unsigned u) { return __uint_as_float(u << 16); }
__device__ inline float bhi(unsigned u) { return __uint_as_float(u & 0xffff0000u); }

// packed 2xf32 ops (VOP3P; halves independent)
__device__ inline void pkfma(v2f& d, v2f a, v2f b) {
    asm("v_pk_fma_f32 %0, %1, %2, %0" : "+v"(d) : "v"(a), "v"(b));
}
__device__ inline void pkadd(v2f& d, v2f a) {
    asm("v_pk_add_f32 %0, %1, %0" : "+v"(d) : "v"(a));
}

// accumulate one edge's 8 bf16 dims (uint4) with UNscaled integer weight (r>>17).
// 2^-15 scale folded into epilogue (exact pow2 -> bit-identical). Zero rec -> w=0.
__device__ inline void accP(v2f& sA, v2f& sB, v2f& sC, v2f& sD, uint4 g, unsigned r) {
    float w = (float)(r >> 17);
    v2f w2 = {w, w};
    v2f e0 = {blo(g.x), bhi(g.x)};
    v2f e1 = {blo(g.y), bhi(g.y)};
    v2f e2 = {blo(g.z), bhi(g.z)};
    v2f e3 = {blo(g.w), bhi(g.w)};
    pkfma(sA, e0, w2);
    pkfma(sB, e1, w2);
    pkfma(sC, e2, w2);
    pkfma(sD, e3, w2);
}

// gather one uint4 (8 bf16 dims) of node src at dim-octet byte offset dOff.
__device__ inline uint4 gath(const unsigned char* __restrict__ base, unsigned r, unsigned dOff) {
    unsigned off = ((r & 0x1FFFFu) << 7) + dOff;
    return *(const uint4*)(base + off);
}

// butterfly reduce across eg (xor 8,16,32) on a packed pair
__device__ inline void wred(v2f& s) {
    v2f t;
    t.x = __shfl_xor(s.x, 8, 64);  t.y = __shfl_xor(s.y, 8, 64);  pkadd(s, t);
    t.x = __shfl_xor(s.x, 16, 64); t.y = __shfl_xor(s.y, 16, 64); pkadd(s, t);
    t.x = __shfl_xor(s.x, 32, 64); t.y = __shfl_xor(s.y, 32, 64); pkadd(s, t);
}

// ---- shared pull body (R1/R7-proven, 50.7us @154MB — ROOFLINE): one WAVE per
// dst node. lane = (eg=lane>>3, d8=lane&7). dwordx4 record loads. cnt is the
// PADDED run length (mult of 4; pads are zero records -> w=0, row-0 gather).
__device__ inline void pull_node(const unsigned char* __restrict__ A16,
                                 unsigned* __restrict__ B16,
                                 const unsigned* __restrict__ sorted,
                                 int node, int start, int cnt, int lane) {
    int eg = lane >> 3;
    int d8 = lane & 7;
    unsigned dOff = (unsigned)d8 << 4;
    const unsigned* ep = sorted + start;     // 16B-aligned (partB pads)

    v2f sA = {0.f,0.f}, sB = {0.f,0.f}, sC = {0.f,0.f}, sD = {0.f,0.f};
    int j = 0;
    while (j + 32 <= cnt) {
        uint4 R = *(const uint4*)(ep + j + (eg << 2));   // records j+4eg..j+4eg+3
        uint4 g0 = gath(A16, R.x, dOff);
        uint4 g1 = gath(A16, R.y, dOff);
        uint4 g2 = gath(A16, R.z, dOff);
        uint4 g3 = gath(A16, R.w, dOff);
        accP(sA, sB, sC, sD, g0, R.x);
        accP(sA, sB, sC, sD, g1, R.y);
        accP(sA, sB, sC, sD, g2, R.z);
        accP(sA, sB, sC, sD, g3, R.w);
        j += 32;
    }
    int rem = cnt - j;                  // 0..28, mult of 4
    if (rem >= 16) {
        uint2 R = *(const uint2*)(ep + j + (eg << 1));   // records j+2eg, j+2eg+1
        uint4 g0 = gath(A16, R.x, dOff);
        uint4 g1 = gath(A16, R.y, dOff);
        accP(sA, sB, sC, sD, g0, R.x);
        accP(sA, sB, sC, sD, g1, R.y);
        j += 16; rem -= 16;
    }
    if (rem > 0) {                      // 4/8/12 records, one predicated round
        int i0 = j + eg, i1 = j + 8 + eg;
        unsigned r0 = (i0 < cnt) ? ep[i0] : 0u;   // r=0 -> w=0
        unsigned r1 = (i1 < cnt) ? ep[i1] : 0u;
        uint4 g0 = gath(A16, r0, dOff);
        uint4 g1 = gath(A16, r1, dOff);
        accP(sA, sB, sC, sD, g0, r0);
        accP(sA, sB, sC, sD, g1, r1);
    }

    wred(sA); wred(sB); wred(sC); wred(sD);

    if (eg == 0) {
        const float k15 = 1.f / 32768.f;   // fold fix15 weight scale (exact pow2)
        uint4 h;
        h.x = bf16pair(sA.x * k15, sA.y * k15);
        h.y = bf16pair(sB.x * k15, sB.y * k15);
        h.z = bf16pair(sC.x * k15, sC.y * k15);
        h.w = bf16pair(sD.x * k15, sD.y * k15);
        *(uint4*)(B16 + (((long long)node) << 5) + (d8 << 2)) = h;
    }
}

// init: E0(bf16) = concat(ue, ie). Block 0 inits bucket cursors.
__global__ void init_emb_kernel(const float* __restrict__ ue,
                                const float* __restrict__ ie,
                                unsigned* __restrict__ E0,
                                int* __restrict__ bucketCursor) {
    int idx = blockIdx.x * blockDim.x + threadIdx.x;   // per float4 (4 dims)
    if (blockIdx.x == 0 && threadIdx.x < 256) {
        bucketCursor[threadIdx.x]       = threadIdx.x * CAP;
        bucketCursor[threadIdx.x + 256] = (threadIdx.x + 256) * CAP;
    }
    const int total = N_NODES * (EMB_DIM / 4);
    if (idx >= total) return;
    const int uoff = NUM_USERS * (EMB_DIM / 4);
    float4 v;
    if (idx < uoff) v = ((const float4*)ue)[idx];
    else            v = ((const float4*)ie)[idx - uoff];
    uint2 h;
    h.x = bf16pair(v.x, v.y);
    h.y = bf16pair(v.z, v.w);
    ((uint2*)E0)[idx] = h;
}

// partA: counting-sort each 4096-edge tile by bucket in LDS (R8-proven), then
// write contiguous per-bucket segments as TWO coalesced streams: rec32 (4B) and
// dl (1B) -> 5B/edge instead of 8. One global atomicAdd per (bucket, tile).
// Scan is wave-shuffle based: 2 barriers instead of 18.
__global__ void partA_kernel(const float* __restrict__ ev,
                             const int*  __restrict__ es,
                             const int*  __restrict__ ed,
                             int* __restrict__ bucketCursor,
                             unsigned* __restrict__ tmpR,
                             unsigned char* __restrict__ tmpD) {
    __shared__ ull  recs[TILE_EDGES];      // 32KB
    __shared__ int  hist[NBUCK];
    __shared__ int  incl[NBUCK];           // inclusive scan of hist
    __shared__ int  gbase[NBUCK];
    __shared__ int  cur[NBUCK];
    __shared__ int  wpart[8];
    int tid = threadIdx.x;                 // 1024
    int e0 = blockIdx.x * TILE_EDGES;
    int nEdge = NNZ - e0; if (nEdge > TILE_EDGES) nEdge = TILE_EDGES;

    if (tid < NBUCK) hist[tid] = 0;
    __syncthreads();

    ull myRec[4]; int myB[4]; int nMy = 0;
    #pragma unroll
    for (int k = 0; k < 4; ++k) {
        int e = e0 + k * 1024 + tid;
        if (e < NNZ) {
            int dst = ed[e];
            unsigned q = (unsigned)fminf(ev[e] * 32768.f + 0.5f, 32767.f);
            unsigned rec = (unsigned)es[e] | (q << 17);
            int b = ((unsigned)dst) >> ABITS;
            myRec[k] = (ull)rec | ((ull)(unsigned)(dst & (NODES_PER_BUCK - 1)) << 32)
                     | ((ull)(unsigned)b << 40);
            myB[k] = b;
            nMy = k + 1;                   // e grows with k -> contiguous prefix
            atomicAdd(&hist[b], 1);
        }
    }
    __syncthreads();

    // inclusive scan of hist[0..511]: wave shuffle scan + cross-wave partials
    {
        int v = (tid < NBUCK) ? hist[tid] : 0;
        #pragma unroll
        for (int o = 1; o < 64; o <<= 1) {
            int n = __shfl_up(v, o, 64);
            if ((tid & 63) >= o) v += n;
        }
        if (tid < NBUCK && (tid & 63) == 63) wpart[tid >> 6] = v;
        __syncthreads();
        if (tid < NBUCK) {
            int add = 0, w = tid >> 6;
            #pragma unroll
            for (int i = 0; i < 8; ++i) if (i < w) add += wpart[i];
            incl[tid] = v + add;
        }
        __syncthreads();
    }
    if (tid < NBUCK) {
        int c = hist[tid];
        cur[tid] = incl[tid] - c;          // local segment start (exclusive scan)
        gbase[tid] = c ? atomicAdd(&bucketCursor[tid], c) : 0;
    }
    __syncthreads();

    for (int k = 0; k < nMy; ++k) {        // LDS scatter (cheap, on-chip)
        int p = atomicAdd(&cur[myB[k]], 1);
        recs[p] = myRec[k];
    }
    __syncthreads();

    for (int p = tid; p < nEdge; p += 1024) {   // coalesced segment copy-out
        ull r = recs[p];
        int b = (int)((r >> 40) & 511u);
        int local = p - (incl[b] - hist[b]);
        int gpos = gbase[b] + local;
        if (gpos < (b + 1) * CAP) {        // overflow guard (stat. unreachable)
            tmpR[gpos] = (unsigned)r;
            tmpD[gpos] = (unsigned char)(r >> 32);
        }
    }
}

// partB: per bucket — 256-node histogram, wave-shuffle scan of pad4(count),
// scatter final records to padded positions; pads zeroed.
// deg[node] = PADDED run length (mult of 4). rowStart 16B-aligned.
__global__ void partB_kernel(const unsigned* __restrict__ tmpR,
                             const unsigned char* __restrict__ tmpD,
                             const int* __restrict__ bucketCursor,
                             int* __restrict__ rowStart,
                             int* __restrict__ deg,
                             unsigned* __restrict__ sorted) {
    __shared__ int cnt[NODES_PER_BUCK];
    __shared__ int nstart[NODES_PER_BUCK];
    __shared__ int cur[NODES_PER_BUCK];
    __shared__ int wpart[4];
    int b = blockIdx.x;
    int tid = threadIdx.x;           // 1024
    int nodeLo = b << ABITS;
    int startE = b * CAP;
    int endE   = bucketCursor[b];    // base + records in bucket

    if (tid < NODES_PER_BUCK) cnt[tid] = 0;
    __syncthreads();

    unsigned myRec[9];
    int myDl[9];
    int nRec = 0;
    #pragma unroll
    for (int k = 0; k < 9; ++k) {
        int i = startE + k * 1024 + tid;
        if (i < endE) {
            myRec[k] = tmpR[i];
            myDl[k]  = (int)tmpD[i];
            nRec = k + 1;
            atomicAdd(&cnt[myDl[k]], 1);
        }
    }
    __syncthreads();

    // scan pad4(cnt) over 256 cells: wave shuffle scan + cross-wave partials
    int p4 = 0, v = 0;
    if (tid < NODES_PER_BUCK) { p4 = (cnt[tid] + 3) & ~3; v = p4; }
    #pragma unroll
    for (int o = 1; o < 64; o <<= 1) {
        int n = __shfl_up(v, o, 64);
        if ((tid & 63) >= o) v += n;
    }
    if (tid < NODES_PER_BUCK && (tid & 63) == 63) wpart[tid >> 6] = v;
    __syncthreads();
    if (tid < NODES_PER_BUCK) {
        int add = 0, w = tid >> 6;
        #pragma unroll
        for (int i = 0; i < 4; ++i) if (i < w) add += wpart[i];
        v += add;                          // inclusive scan value
        int ns = startE + v - p4;          // 16B-aligned (startE%4==0, scan of x4)
        nstart[tid] = ns;
        cur[tid] = ns;
        int node = nodeLo + tid;
        if (node < N_NODES) {
            rowStart[node] = ns;
            deg[node] = p4;                // PADDED length; pads zeroed below
        }
    }
    __syncthreads();

    for (int k = 0; k < nRec; ++k) {
        int pos = atomicAdd(&cur[myDl[k]], 1);
        if (pos < startE + CAP) sorted[pos] = myRec[k];  // overflow guard
    }
    __syncthreads();

    if (tid < NODES_PER_BUCK) {        // zero the <=3 pad slots at each node tail
        int end = nstart[tid] + ((cnt[tid] + 3) & ~3);
        for (int p = cur[tid]; p < end; ++p)
            if (p < startE + CAP) sorted[p] = 0;
    }
}

// ---- pull_sync (ungated layers): one wave per node.
__global__ void pull_sync_kernel(const unsigned char* __restrict__ A16,
                                 unsigned* __restrict__ B16,
                                 const unsigned* __restrict__ sorted,
                                 const int* __restrict__ rowStart,
                                 const int* __restrict__ deg) {
    int t = blockIdx.x * blockDim.x + threadIdx.x;
    int node = __builtin_amdgcn_readfirstlane(t >> 6);
    if (node >= N_NODES) return;
    int start = rowStart[node];        // scalar (node in SGPR)
    int cnt   = deg[node];
    pull_node(A16, B16, sorted, node, start, cnt, t & 63);
}

// ---- pull_gated (layer 3): one wave per batch ENTRY (dense sweep of the 32768
// user/item indices — no flags, no dead waves). Duplicate entries store
// byte-identical rows (benign race).
__global__ void pull_gated_kernel(const unsigned char* __restrict__ A16,
                                  unsigned* __restrict__ B16,
                                  const unsigned* __restrict__ sorted,
                                  const int* __restrict__ rowStart,
                                  const int* __restrict__ deg,
                                  const int* __restrict__ users,
                                  const int* __restrict__ items) {
    int t = blockIdx.x * blockDim.x + threadIdx.x;
    int e = __builtin_amdgcn_readfirstlane(t >> 6);
    if (e >= 2 * BATCH) return;
    int node = (e < BATCH) ? users[e] : (NUM_USERS + items[e - BATCH]);
    node = __builtin_amdgcn_readfirstlane(node);
    int start = rowStart[node];
    int cnt   = deg[node];
    pull_node(A16, B16, sorted, node, start, cnt, t & 63);
}

// dot: half-wave (32 lanes) per batch element; lane covers 2 dims (one uint).
// gamma = dot( sum_l U_l , sum_l I_l ) / 16, layers read from E0,B1,B2,B3.
__global__ void dot_kernel(const unsigned* __restrict__ E0,
                           const unsigned* __restrict__ B1,
                           const unsigned* __restrict__ B2,
                           const unsigned* __restrict__ B3,
                           const int* __restrict__ users,
                           const int* __restrict__ items,
                           float* __restrict__ out) {
    int t = blockIdx.x * blockDim.x + threadIdx.x;
    int b = t >> 5;
    int lane = t & 31;
    if (b >= BATCH) return;
    long long uo = ((long long)users[b] << 5) + lane;
    long long io = ((long long)(items[b] + NUM_USERS) << 5) + lane;
    unsigned a0 = E0[uo], a1 = B1[uo], a2 = B2[uo], a3 = B3[uo];
    unsigned c0 = E0[io], c1 = B1[io], c2 = B2[io], c3 = B3[io];
    float ux = (blo(a0) + blo(a1)) + (blo(a2) + blo(a3));
    float uy = (bhi(a0) + bhi(a1)) + (bhi(a2) + bhi(a3));
    float ix = (blo(c0) + blo(c1)) + (blo(c2) + blo(c3));
    float iy = (bhi(c0) + bhi(c1)) + (bhi(c2) + bhi(c3));
    float p = ux * ix + uy * iy;
    #pragma unroll
    for (int off = 16; off >= 1; off >>= 1)
        p += __shfl_xor(p, off, 64);   // stays within the aligned 32-group
    if (lane == 0) out[b] = p * 0.0625f;
}

extern "C" void kernel_launch(void* const* d_in, const int* in_sizes, int n_in,
                              void* d_out, int out_size, void* d_ws, size_t ws_size,
                              hipStream_t stream) {
    const float* user_emb = (const float*)d_in[0];
    const float* item_emb = (const float*)d_in[1];
    const float* edge_val = (const float*)d_in[2];
    const int*   edge_src = (const int*)d_in[3];
    const int*   edge_dst = (const int*)d_in[4];
    const int*   users    = (const int*)d_in[5];
    const int*   items    = (const int*)d_in[6];
    float* out = (float*)d_out;

    const size_t emb16Bytes = (size_t)N_NODES * EMB_DIM * 2;               // 12.8 MB
    const size_t sortBytes  = (size_t)NBUCK_USED * CAP * sizeof(unsigned); // 14.8 MB
    const size_t tmpRBytes  = (size_t)NBUCK_USED * CAP * sizeof(unsigned); // 14.8 MB
    const size_t tmpDBytes  = (size_t)NBUCK_USED * CAP;                    //  3.7 MB
    const size_t nodeBytes  = (size_t)N_NODES * sizeof(int);               // 400 KB

    char* w = (char*)d_ws;
    unsigned* E0           = (unsigned*)(w); w += emb16Bytes;
    unsigned* B1           = (unsigned*)(w); w += emb16Bytes;
    unsigned* B2           = (unsigned*)(w); w += emb16Bytes;
    unsigned* B3           = (unsigned*)(w); w += emb16Bytes;
    unsigned* sorted       = (unsigned*)(w); w += sortBytes;
    unsigned* tmpR         = (unsigned*)(w); w += tmpRBytes;
    unsigned char* tmpD    = (unsigned char*)(w); w += (tmpDBytes + 15) & ~15ull;
    int*      deg          = (int*)(w);      w += nodeBytes;
    int*      rowStart     = (int*)(w);      w += nodeBytes;
    int*      bucketCursor = (int*)(w);      w += NBUCK * sizeof(int);

    const int vecTotal   = N_NODES * (EMB_DIM / 4);
    const int initBlocks = (vecTotal + 255) / 256;
    const int tileBlocks = (NNZ + TILE_EDGES - 1) / TILE_EDGES;   // 782

    init_emb_kernel<<<initBlocks, 256, 0, stream>>>(user_emb, item_emb, E0, bucketCursor);

    partA_kernel<<<tileBlocks, 1024, 0, stream>>>(edge_val, edge_src, edge_dst,
                                                  bucketCursor, tmpR, tmpD);
    partB_kernel<<<NBUCK_USED, 1024, 0, stream>>>(tmpR, tmpD, bucketCursor,
                                                  rowStart, deg, sorted);

    const int pullBlocks = (N_NODES * 64 + 255) / 256;            // 1 node/wave
    pull_sync_kernel<<<pullBlocks, 256, 0, stream>>>((const unsigned char*)E0, B1,
                                                     sorted, rowStart, deg);
    pull_sync_kernel<<<pullBlocks, 256, 0, stream>>>((const unsigned char*)B1, B2,
                                                     sorted, rowStart, deg);

    const int gatedBlocks = (2 * BATCH * 64 + 255) / 256;         // 1 entry/wave
    pull_gated_kernel<<<gatedBlocks, 256, 0, stream>>>((const unsigned char*)B2, B3,
                                                       sorted, rowStart, deg, users, items);

    const int dotBlocks = (BATCH * 32 + 255) / 256;
    dot_kernel<<<dotBlocks, 256, 0, stream>>>(E0, B1, B2, B3, users, items, out);
}